// Round 2
// 287.481 us; speedup vs baseline: 1.1132x; 1.1132x over previous
//
#include <hip/hip_runtime.h>
#include <math.h>

// Problem constants (from setup_inputs): B=64, S=4096, D=128.
#define NB 64
#define NS 4096
#define ND 128
#define NPTS (NB * NS)          // 262144 points
#define PPB 256                 // points per block in K1/K3/K5
#define NBLK (NPTS / PPB)       // 1024 blocks
#define EPSV 1e-5f
#define CLAMPV 1e-8f
#define MAXEUC 32.0f

__device__ __forceinline__ float rcp_f(float x) { return __builtin_amdgcn_rcpf(x); }

// v += row_ror(v, N) — full-rate VALU DPP, no LDS pipe.
#define DPP_ADD(v, ctrl)                                                            \
    v += __int_as_float(__builtin_amdgcn_update_dpp(0, __float_as_int(v), (ctrl),   \
                                                    0xF, 0xF, true))

// Sum across each 16-lane row; every lane of the row gets the total.
__device__ __forceinline__ float row16_sum(float v) {
    DPP_ADD(v, 0x128);  // ror:8
    DPP_ADD(v, 0x124);  // ror:4
    DPP_ADD(v, 0x122);  // ror:2
    DPP_ADD(v, 0x121);  // ror:1
    return v;
}

// Per-point scalars, 16-lane-per-point layout. Lane fl holds x float4s a,b.
// alpha = clip(2 m0 x0 - dot(m,x), 1+1e-7) via weighted dot (weight +m0 on slot0)
// fac = acosh(alpha)/sqrt(alpha^2-1);  hcoef = -fac*(alpha+x0)/(1+m0)
__device__ __forceinline__ void point_scalars16(const float4& xa, const float4& xb,
                                                const float4& wa, const float4& wb,
                                                float inv1pm0, int fl,
                                                float& fac, float& hcoef) {
    float ad = wa.x * xa.x + wa.y * xa.y + wa.z * xa.z + wa.w * xa.w
             + wb.x * xb.x + wb.y * xb.y + wb.z * xb.z + wb.w * xb.w;
    float px = (fl == 0) ? xa.x : 0.f;
    ad = row16_sum(ad);          // = 2 m0 x0 - dot(m,x)
    px = row16_sum(px);          // = x0
    float alpha = fmaxf(ad, 1.0f + 1e-7f);
    float am1 = alpha * alpha - 1.f;
    float sq = sqrtf(fmaxf(am1, CLAMPV));
    fac = __logf(alpha + sq) * rcp_f(sq);           // acosh(alpha)/unorm
    hcoef = -fac * (alpha + px) * inv1pm0;
}

// ---------------- K1: per-block sums of x over its 256-point slice (16-lane layout)
__global__ __launch_bounds__(256) void k1(const float4* __restrict__ x4,
                                          float* __restrict__ part1) {
    const int fl = threadIdx.x & 15;
    const int pg = threadIdx.x >> 4;
    const long long base = (long long)blockIdx.x * PPB;
    float4 sa = make_float4(0.f, 0.f, 0.f, 0.f), sb = sa;
#pragma unroll 4
    for (int i = 0; i < PPB / 16; ++i) {
        long long p = base + i * 16 + pg;
        float4 xa = x4[p * 32 + fl];
        float4 xb = x4[p * 32 + fl + 16];
        sa.x += xa.x; sa.y += xa.y; sa.z += xa.z; sa.w += xa.w;
        sb.x += xb.x; sb.y += xb.y; sb.z += xb.z; sb.w += xb.w;
    }
    __shared__ float ls[16][ND];
    float* ps = &ls[pg][fl * 8];
    ps[0] = sa.x; ps[1] = sa.y; ps[2] = sa.z; ps[3] = sa.w;
    ps[4] = sb.x; ps[5] = sb.y; ps[6] = sb.z; ps[7] = sb.w;
    __syncthreads();
    if (threadIdx.x < ND) {
        int d = threadIdx.x;
        int slot = ((d & 63) >> 2) * 8 + (d >> 6) * 4 + (d & 3);
        float S = 0.f;
#pragma unroll
        for (int cc = 0; cc < 16; ++cc) S += ls[cc][slot];
        part1[blockIdx.x * ND + d] = S;
    }
}

// ---------------- K2a: 64 blocks, one per-batch Lorentz centroid each
__global__ __launch_bounds__(64) void k2a(const float* __restrict__ part1,
                                          float* __restrict__ avg1) {
    const int b = blockIdx.x;
    const int t = threadIdx.x;   // feature t and t+64
    float a0 = 0.f, a1 = 0.f;
#pragma unroll
    for (int c = 0; c < 16; ++c) {          // 16 point-blocks per batch
        a0 += part1[(b * 16 + c) * ND + t];
        a1 += part1[(b * 16 + c) * ND + 64 + t];
    }
    a0 *= (1.0f / (float)NS);
    a1 *= (1.0f / (float)NS);
    float s = a0 * a0 + a1 * a1;
#pragma unroll
    for (int o = 32; o > 0; o >>= 1) s += __shfl_xor(s, o, 64);
    float a00 = __shfl(a0, 0, 64);
    float denom = sqrtf(fmaxf(2.f * a00 * a00 - s, CLAMPV));
    avg1[b * ND + t] = a0 / denom;
    avg1[b * ND + 64 + t] = a1 / denom;
}

// ---------------- K2b: final centroid of the 64 centroids -> meanG (D,)
__global__ __launch_bounds__(64) void k2b(const float* __restrict__ avg1,
                                          float* __restrict__ meanG) {
    const int t = threadIdx.x;
    float a0 = 0.f, a1 = 0.f;
    for (int b = 0; b < NB; ++b) {
        a0 += avg1[b * ND + t];
        a1 += avg1[b * ND + 64 + t];
    }
    a0 *= (1.0f / (float)NB);
    a1 *= (1.0f / (float)NB);
    float s = a0 * a0 + a1 * a1;
#pragma unroll
    for (int o = 32; o > 0; o >>= 1) s += __shfl_xor(s, o, 64);
    float a00 = __shfl(a0, 0, 64);
    float denom = sqrtf(fmaxf(2.f * a00 * a00 - s, CLAMPV));
    meanG[t] = a0 / denom;
    meanG[64 + t] = a1 / denom;
}

// ---------------- K3: per-feature sum/sumsq of x_T (feature-major partials);
//                     also cache per-point fac/hc for K5.
__global__ __launch_bounds__(256) void k3(const float4* __restrict__ x4,
                                          const float* __restrict__ meanG,
                                          float* __restrict__ p3S,
                                          float* __restrict__ p3Q,
                                          float2* __restrict__ fchG) {
    const int fl = threadIdx.x & 15;
    const int pg = threadIdx.x >> 4;
    const float4* m4 = (const float4*)meanG;
    const float4 ma = m4[fl], mb = m4[fl + 16];
    const float m0 = meanG[0];
    const float inv1pm0 = rcp_f(1.f + m0);
    float4 wa = make_float4(-ma.x, -ma.y, -ma.z, -ma.w);
    float4 wb = make_float4(-mb.x, -mb.y, -mb.z, -mb.w);
    if (fl == 0) wa.x = ma.x;            // weight +m0 on the time slot
    float4 sa = make_float4(0.f, 0.f, 0.f, 0.f), sb = sa, qa = sa, qb = sa;
    const long long base = (long long)blockIdx.x * PPB;
#pragma unroll 4
    for (int i = 0; i < PPB / 16; ++i) {
        long long p = base + i * 16 + pg;
        float4 xa = x4[p * 32 + fl];
        float4 xb = x4[p * 32 + fl + 16];
        float fac, hc;
        point_scalars16(xa, xb, wa, wb, inv1pm0, fl, fac, hc);
        if (fl == 0) fchG[p] = make_float2(fac, hc);
        float t0 = fac * xa.x + hc * ma.x;
        float t1 = fac * xa.y + hc * ma.y;
        float t2 = fac * xa.z + hc * ma.z;
        float t3 = fac * xa.w + hc * ma.w;
        float t4 = fac * xb.x + hc * mb.x;
        float t5 = fac * xb.y + hc * mb.y;
        float t6 = fac * xb.z + hc * mb.z;
        float t7 = fac * xb.w + hc * mb.w;
        if (fl == 0) t0 = 0.f;           // time component exactly 0
        sa.x += t0; sa.y += t1; sa.z += t2; sa.w += t3;
        sb.x += t4; sb.y += t5; sb.z += t6; sb.w += t7;
        qa.x += t0 * t0; qa.y += t1 * t1; qa.z += t2 * t2; qa.w += t3 * t3;
        qb.x += t4 * t4; qb.y += t5 * t5; qb.z += t6 * t6; qb.w += t7 * t7;
    }
    __shared__ float ls[16][ND];
    __shared__ float lq[16][ND];
    float* ps = &ls[pg][fl * 8];
    float* pq = &lq[pg][fl * 8];
    ps[0] = sa.x; ps[1] = sa.y; ps[2] = sa.z; ps[3] = sa.w;
    ps[4] = sb.x; ps[5] = sb.y; ps[6] = sb.z; ps[7] = sb.w;
    pq[0] = qa.x; pq[1] = qa.y; pq[2] = qa.z; pq[3] = qa.w;
    pq[4] = qb.x; pq[5] = qb.y; pq[6] = qb.z; pq[7] = qb.w;
    __syncthreads();
    if (threadIdx.x < ND) {
        int d = threadIdx.x;
        int slot = ((d & 63) >> 2) * 8 + (d >> 6) * 4 + (d & 3);
        float S = 0.f, Q = 0.f;
#pragma unroll
        for (int cc = 0; cc < 16; ++cc) { S += ls[cc][slot]; Q += lq[cc][slot]; }
        p3S[d * NBLK + blockIdx.x] = S;  // feature-major for contiguous K4 reads
        p3Q[d * NBLK + blockIdx.x] = Q;
    }
}

// ---------------- K4: 128 blocks, one feature each -> scale = gamma/(std+eps)
__global__ __launch_bounds__(256) void k4(const float* __restrict__ p3S,
                                          const float* __restrict__ p3Q,
                                          const float* __restrict__ gamma,
                                          float* __restrict__ scaleG) {
    const int d = blockIdx.x;
    const int t = threadIdx.x;
    const float4* vS = (const float4*)(p3S + d * NBLK);
    const float4* vQ = (const float4*)(p3Q + d * NBLK);
    float4 a = vS[t];                    // 256 threads * float4 = 1024 partials
    float4 b = vQ[t];
    __shared__ double dredS[256];
    __shared__ double dredQ[256];
    dredS[t] = (double)a.x + (double)a.y + (double)a.z + (double)a.w;
    dredQ[t] = (double)b.x + (double)b.y + (double)b.z + (double)b.w;
    __syncthreads();
    for (int o = 128; o > 0; o >>= 1) {
        if (t < o) { dredS[t] += dredS[t + o]; dredQ[t] += dredQ[t + o]; }
        __syncthreads();
    }
    if (t == 0) {
        const double N = (double)NPTS;
        double mu = dredS[0] / N;
        double var = dredQ[0] / N - mu * mu;
        if (var < 0.0) var = 0.0;
        float stdv = sqrtf((float)var + EPSV);
        scaleG[d] = gamma[d] / (stdv + EPSV);
    }
}

// ---------------- K5: scale, rescale, transp0(beta), expmap(beta) -> out
__global__ __launch_bounds__(256) void k5(const float4* __restrict__ x4,
                                          const float* __restrict__ meanG,
                                          const float* __restrict__ scaleG,
                                          const float* __restrict__ betaG,
                                          const float2* __restrict__ fchG,
                                          float4* __restrict__ out4) {
    const int fl = threadIdx.x & 15;
    const int pg = threadIdx.x >> 4;
    const float4* m4 = (const float4*)meanG;
    const float4* s4 = (const float4*)scaleG;
    const float4* b4 = (const float4*)betaG;
    const float4 ma = m4[fl], mb = m4[fl + 16];
    const float4 sca = s4[fl], scb = s4[fl + 16];
    const float4 bta = b4[fl], btb = b4[fl + 16];
    const float b0 = betaG[0];
    const float inv1pb0 = rcp_f(1.f + b0);
    const long long base = (long long)blockIdx.x * PPB;
#pragma unroll 4
    for (int i = 0; i < PPB / 16; ++i) {
        long long p = base + i * 16 + pg;
        float4 xa = x4[p * 32 + fl];
        float4 xb = x4[p * 32 + fl + 16];
        float2 fh = fchG[p];             // cached in K3 — no dot/DPP/log chain here
        float fac = fh.x, hc = fh.y;
        float ts0 = sca.x * (fac * xa.x + hc * ma.x);
        float ts1 = sca.y * (fac * xa.y + hc * ma.y);
        float ts2 = sca.z * (fac * xa.z + hc * ma.z);
        float ts3 = sca.w * (fac * xa.w + hc * ma.w);
        float ts4 = scb.x * (fac * xb.x + hc * mb.x);
        float ts5 = scb.y * (fac * xb.y + hc * mb.y);
        float ts6 = scb.z * (fac * xb.z + hc * mb.z);
        float ts7 = scb.w * (fac * xb.w + hc * mb.w);
        if (fl == 0) ts0 = 0.f;
        // fused reductions: nn = ||ts||^2 ; bd = <beta_s, ts_s> (pre-rescale)
        float nn = ts0 * ts0 + ts1 * ts1 + ts2 * ts2 + ts3 * ts3
                 + ts4 * ts4 + ts5 * ts5 + ts6 * ts6 + ts7 * ts7;
        float bd = bta.x * ts0 + bta.y * ts1 + bta.z * ts2 + bta.w * ts3
                 + btb.x * ts4 + btb.y * ts5 + btb.z * ts6 + btb.w * ts7;
        nn = row16_sum(nn);
        bd = row16_sum(bd);
        float n = sqrtf(nn);
        float r = fminf(1.f, MAXEUC * rcp_f(fmaxf(n, CLAMPV)));
        float coef2 = r * bd * inv1pb0;            // transp0(beta) coefficient
        float nu = fmaxf(r * n, 1e-4f);            // sqrt(clip((r n)^2, 1e-8))
        float e = __expf(nu);
        float ei = rcp_f(e);
        float ch = 0.5f * (e + ei);
        float sf = (0.5f * (e - ei)) * rcp_f(nu);  // sinh(nu)/nu
        float A = ch + sf * coef2;
        float Bc = sf * r;
        float4 oa, ob;
        oa.x = Bc * ts0 + A * bta.x;
        oa.y = Bc * ts1 + A * bta.y;
        oa.z = Bc * ts2 + A * bta.z;
        oa.w = Bc * ts3 + A * bta.w;
        ob.x = Bc * ts4 + A * btb.x;
        ob.y = Bc * ts5 + A * btb.y;
        ob.z = Bc * ts6 + A * btb.z;
        ob.w = Bc * ts7 + A * btb.w;
        if (fl == 0) oa.x += sf * coef2;           // the "+o" time slot
        out4[p * 32 + fl] = oa;
        out4[p * 32 + fl + 16] = ob;
    }
}

extern "C" void kernel_launch(void* const* d_in, const int* in_sizes, int n_in,
                              void* d_out, int out_size, void* d_ws, size_t ws_size,
                              hipStream_t stream) {
    const float* x = (const float*)d_in[0];
    const float* gamma = (const float*)d_in[1];
    const float* beta = (const float*)d_in[2];
    float* out = (float*)d_out;
    float* ws = (float*)d_ws;

    // workspace layout (floats); harness workspace is 512 MiB — ample.
    float* part1  = ws;                        // NBLK*ND       = 131072
    float* avg1   = part1 + NBLK * ND;         // NB*ND         = 8192
    float* meanG  = avg1 + NB * ND;            // 128
    float* scaleG = meanG + ND;                // 128
    float* p3S    = scaleG + ND;               // ND*NBLK       = 131072 (feature-major)
    float* p3Q    = p3S + ND * NBLK;           // ND*NBLK       = 131072
    float2* fchG  = (float2*)(p3Q + ND * NBLK);// NPTS float2   = 2 MB

    k1 <<<NBLK, 256, 0, stream>>>((const float4*)x, part1);
    k2a<<<NB, 64, 0, stream>>>(part1, avg1);
    k2b<<<1, 64, 0, stream>>>(avg1, meanG);
    k3 <<<NBLK, 256, 0, stream>>>((const float4*)x, meanG, p3S, p3Q, fchG);
    k4 <<<ND, 256, 0, stream>>>(p3S, p3Q, gamma, scaleG);
    k5 <<<NBLK, 256, 0, stream>>>((const float4*)x, meanG, scaleG, beta, fchG,
                                  (float4*)out);
}